// Round 13
// baseline (191.552 us; speedup 1.0000x reference)
//
#include <hip/hip_runtime.h>

// phase modulation, real-part output: out = x_r*cos(2*pi*p) - x_i*sin(2*pi*p)
// inside centered 256x256 window; out = x_r elsewhere.
// R7/R10/R11 all pin at ~2-2.5 TB/s, VALU 13-19%: issue/latency-bound. Root
// cause: divergent loads (exec-mask serialization) + 50-instr ocml sincos.
// R12/R13: fully branchless. Unconditional xr/xi/phase loads (clamped addr),
// select p_eff=0 outside (sin=0,cos=1 -> out=x_r exactly), HW v_sin/v_cos via
// inline asm (input in REVOLUTIONS = p directly; v_fract_f32 reduce per ISA
// doc; HW err ~1e-5 << passing absmax 0.0156). Plain stores (R7 best).

constexpr int M = 512;
constexpr int N = 256;
constexpr int START = 128;
constexpr int CH = 9;

__device__ __forceinline__ float hw_sin_rev(float f) {   // sin(2*pi*f), f in [0,1)
    float r;
    asm("v_sin_f32 %0, %1" : "=v"(r) : "v"(f));
    return r;
}
__device__ __forceinline__ float hw_cos_rev(float f) {   // cos(2*pi*f), f in [0,1)
    float r;
    asm("v_cos_f32 %0, %1" : "=v"(r) : "v"(f));
    return r;
}

__device__ __forceinline__ void hw_sincos(float p, float inmask, float& s, float& c) {
    // p in [0,2) revolutions; p_eff = p if inside else 0 -> (s,c)=(0,1) -> out=x_r
    float pe = inmask * p;                 // inmask is 1.0f or 0.0f
    float f  = pe - floorf(pe);            // v_fract_f32: exact for pe in [0,2]
    s = hw_sin_rev(f);
    c = hw_cos_rev(f);
}

__device__ __forceinline__ float4 mod4(float4 r, float4 im, float4 p, float inmask) {
    float s0, c0, s1, c1, s2, c2, s3, c3;
    hw_sincos(p.x, inmask, s0, c0);
    hw_sincos(p.y, inmask, s1, c1);
    hw_sincos(p.z, inmask, s2, c2);
    hw_sincos(p.w, inmask, s3, c3);
    float4 o;
    o.x = r.x * c0 - im.x * s0;
    o.y = r.y * c1 - im.y * s1;
    o.z = r.z * c2 - im.z * s2;
    o.w = r.w * c3 - im.w * s3;
    return o;
}

// Block owns 2048 contiguous floats (4 half-rows). Group0: base + tid*4,
// group1: +1024. col identical for both groups (1024 % 512 == 0); chan
// block-invariant (each block inside one 2^18-elem image). Zero branches.
__global__ __launch_bounds__(256) void phase_mod_real_bl(
    const float* __restrict__ xr,
    const float* __restrict__ xi,
    const float* __restrict__ phase,
    float* __restrict__ out)
{
    const int tid = threadIdx.x;
    const long tile = (long)blockIdx.x * 2048;
    const long e0 = tile + (long)tid * 4;
    const long e1 = e0 + 1024;

    // ---- unconditional load burst: 6 x dwordx4 in flight ----
    float4 r0 = *reinterpret_cast<const float4*>(xr + e0);
    float4 r1 = *reinterpret_cast<const float4*>(xr + e1);
    float4 i0 = *reinterpret_cast<const float4*>(xi + e0);
    float4 i1 = *reinterpret_cast<const float4*>(xi + e1);

    const int col  = (int)(e0 & (M - 1));              // multiple of 4
    const int row0 = (int)((e0 >> 9) & (M - 1));
    const int row1 = row0 + 2;                          // e1 = e0 + 2 rows
    const int chan = (int)((tile >> 18) % CH);

    // clamped (always-valid, 16B-aligned) phase addresses
    const int colc  = min(max(col - START, 0), N - 4);  // multiple of 4 in [0,252]
    const int rm0   = min(max(row0 - START, 0), N - 1);
    const int rm1   = min(max(row1 - START, 0), N - 1);
    const long pbase = (long)chan * (N * N) + colc;
    float4 p0 = *reinterpret_cast<const float4*>(phase + pbase + (long)rm0 * N);
    float4 p1 = *reinterpret_cast<const float4*>(phase + pbase + (long)rm1 * N);

    const bool colIn = (unsigned)(col - START) < (unsigned)N;
    const float m0 = (colIn && (unsigned)(row0 - START) < (unsigned)N) ? 1.0f : 0.0f;
    const float m1 = (colIn && (unsigned)(row1 - START) < (unsigned)N) ? 1.0f : 0.0f;

    float4 o0 = mod4(r0, i0, p0, m0);
    float4 o1 = mod4(r1, i1, p1, m1);

    *reinterpret_cast<float4*>(out + e0) = o0;
    *reinterpret_cast<float4*>(out + e1) = o1;
}

// ---- mode B (defensive, if out_size >= 2n): interleaved complex64 ----
#define TWO_PI 6.283185307179586f
__global__ __launch_bounds__(256) void phase_mod_cplx_kernel(
    const float* __restrict__ xr,
    const float* __restrict__ xi,
    const float* __restrict__ phase,
    float* __restrict__ out,
    int nvec4)
{
    int t = blockIdx.x * blockDim.x + threadIdx.x;
    if (t >= nvec4) return;
    long e = (long)t * 4;
    int col     = (int)(e & (M - 1));
    int rowflat = (int)(e >> 9);
    int row     = rowflat & (M - 1);

    float4 r  = *reinterpret_cast<const float4*>(xr + e);
    float4 im = *reinterpret_cast<const float4*>(xi + e);
    float4 o0 = make_float4(r.x, im.x, r.y, im.y);
    float4 o1 = make_float4(r.z, im.z, r.w, im.w);

    bool inside = ((unsigned)(row - START) < (unsigned)N) &&
                  ((unsigned)(col - START) < (unsigned)N);
    if (inside) {
        int chan = (rowflat >> 9) % CH;
        long pidx = (long)chan * (N * N) + (long)(row - START) * N + (col - START);
        float4 p = *reinterpret_cast<const float4*>(phase + pidx);
        float s0, c0, s1, c1, s2, c2, s3, c3;
        sincosf(TWO_PI * p.x, &s0, &c0);
        sincosf(TWO_PI * p.y, &s1, &c1);
        sincosf(TWO_PI * p.z, &s2, &c2);
        sincosf(TWO_PI * p.w, &s3, &c3);
        o0.x = r.x * c0 - im.x * s0;  o0.y = r.x * s0 + im.x * c0;
        o0.z = r.y * c1 - im.y * s1;  o0.w = r.y * s1 + im.y * c1;
        o1.x = r.z * c2 - im.z * s2;  o1.y = r.z * s2 + im.z * c2;
        o1.z = r.w * c3 - im.w * s3;  o1.w = r.w * s3 + im.w * c3;
    }
    *reinterpret_cast<float4*>(out + 2 * e)     = o0;
    *reinterpret_cast<float4*>(out + 2 * e + 4) = o1;
}

extern "C" void kernel_launch(void* const* d_in, const int* in_sizes, int n_in,
                              void* d_out, int out_size, void* d_ws, size_t ws_size,
                              hipStream_t stream) {
    const float* xr    = (const float*)d_in[0];
    const float* xi    = (const float*)d_in[1];
    const float* phase = (const float*)d_in[2];
    float* out = (float*)d_out;

    long n = in_sizes[0];            // 18,874,368
    if ((long)out_size >= 2 * n) {
        int nvec4 = (int)(n / 4);
        int grid = (nvec4 + 255) / 256;
        phase_mod_cplx_kernel<<<grid, 256, 0, stream>>>(xr, xi, phase, out, nvec4);
    } else {
        int grid = (int)(n / 2048);                 // 9,216 blocks, exact cover
        phase_mod_real_bl<<<grid, 256, 0, stream>>>(xr, xi, phase, out);
    }
}